// Round 11
// baseline (84.324 us; speedup 1.0000x reference)
//
#include <hip/hip_runtime.h>
#include <math.h>

// TDVP_V2: BATCH=16384 chains, N=64 sites, D=4, DIN=DOUT=2.
// v11: 16 threads/chain (4-site segments) to double occupancy.
//   bb = tid&15 : chain-in-block (16 chains/block)
//   s  = tid>>4 : segment 0..15 (4 sites each); 4 distinct s per wave.
//   grid = 1024 blocks x 256 threads -> 4096 waves -> 4 waves/SIMD
//   (v10 was grid-limited at 2 waves/SIMD; latency-bound per counters).
// __launch_bounds__(256,4) caps VGPR at 128 so 4 blocks/CU co-reside; M is
// rebuilt on use (v9-style) rather than register-cached to fit the budget.
// LDS:
//   sP  [t]*264 + [e]*16 + bb  (fp32 segment products, stride 264:
//        264%32=8 -> the 4 s-subgroups/wave write disjoint-by-8 bank
//        windows -> <=2-way = free; scan reads are same-address 4-lane
//        broadcasts = free)                                   16.9 KB
//   sXY [chain]*130 + 2*site   (coalesced x in / y out, v9-proven) 8.3 KB
// Phases: 1) per-thread 4-site product P_s (normalized) -> sP
//         2) per-thread prefix/suffix vector scans over sP (named scalars
//            only; normalized each step; scale cancels in the H-norm)
//         3a) forward walk (vl per site), 3b) backward walk + epilogue
//             H = vl.B.ar, norm/nan/relu, y = H.xn -> sXY -> coalesced out.

#define EPS 1e-6f

__device__ __forceinline__ void build_M(const float* __restrict__ A, int n,
                                        float xn0, float xn1, float* Mm) {
    const float4* Aq = (const float4*)A + (size_t)n * 8;
    #pragma unroll
    for (int t = 0; t < 8; ++t) {
        const float4 q = Aq[t];
        Mm[2*t]     = fmaf(xn1, q.y, xn0 * q.x);
        Mm[2*t + 1] = fmaf(xn1, q.w, xn0 * q.z);
    }
}

__global__ __launch_bounds__(256, 4)
void tdvp_kernel(const float* __restrict__ x,
                 const float* __restrict__ A,
                 const float* __restrict__ Bw,
                 const float* __restrict__ scale,
                 float* __restrict__ y)
{
    __shared__ float sP[16 * 264];      // [t][e][bb], padded seg stride
    __shared__ float sXY[16 * 130];     // [chain][2*site], padded

    const int tid = threadIdx.x;
    const int bb  = tid & 15;
    const int s   = tid >> 4;           // 0..15
    const int n0  = s * 4;

    // ---- stage x: fully coalesced block load -> sXY ----------------------
    {
        const float4* xg = (const float4*)x + (size_t)blockIdx.x * 512;
        #pragma unroll
        for (int it = 0; it < 2; ++it) {
            const int g = it * 256 + tid;
            const float4 v = xg[g];
            const int c = g >> 5, f = (g & 31) * 4;
            *(float2*)&sXY[c * 130 + f]     = make_float2(v.x, v.y);
            *(float2*)&sXY[c * 130 + f + 2] = make_float2(v.z, v.w);
        }
    }
    __syncthreads();

    // ---- my 4 sites from LDS, normalized --------------------------------
    float xa[4], xc[4];
    #pragma unroll
    for (int k = 0; k < 4; ++k) {
        const float2 v = *(const float2*)&sXY[bb * 130 + 2 * n0 + 2 * k];
        const float inr = 1.f / sqrtf(v.x * v.x + v.y * v.y);
        xa[k] = v.x * inr; xc[k] = v.y * inr;
    }

    // ---- phase 1: segment product P = M[n0..n0+3] (normalized) -> sP ----
    {
        float P[16];
        build_M(A, n0, xa[0], xc[0], P);
        #pragma unroll
        for (int k = 1; k < 4; ++k) {
            float Mm[16];
            build_M(A, n0 + k, xa[k], xc[k], Mm);
            float Pn[16];
            #pragma unroll
            for (int i = 0; i < 4; ++i) {
                #pragma unroll
                for (int j = 0; j < 4; ++j) {
                    float acc = P[i*4] * Mm[j];
                    acc = fmaf(P[i*4+1], Mm[4+j],  acc);
                    acc = fmaf(P[i*4+2], Mm[8+j],  acc);
                    acc = fmaf(P[i*4+3], Mm[12+j], acc);
                    Pn[i*4+j] = acc;
                }
            }
            #pragma unroll
            for (int e = 0; e < 16; ++e) P[e] = Pn[e];
        }
        float ss = 0.f;
        #pragma unroll
        for (int e = 0; e < 16; ++e) ss = fmaf(P[e], P[e], ss);
        const float rn = 1.f / (sqrtf(ss) + 1e-30f);
        #pragma unroll
        for (int e = 0; e < 16; ++e)
            sP[s * 264 + e * 16 + bb] = P[e] * rn;
    }
    __syncthreads();

    // ---- phase 2: per-thread prefix / suffix vector scans ---------------
    float v0 = 1.f, v1 = 0.f, v2 = 0.f, v3 = 0.f;
    #pragma unroll 1
    for (int t = 0; t < s; ++t) {
        const float* pp = &sP[t * 264 + bb];
        const float p0  = pp[0],    p1  = pp[16],   p2  = pp[32],   p3  = pp[48];
        const float p4  = pp[64],   p5  = pp[80],   p6  = pp[96],   p7  = pp[112];
        const float p8  = pp[128],  p9  = pp[144],  p10 = pp[160],  p11 = pp[176];
        const float p12 = pp[192],  p13 = pp[208],  p14 = pp[224],  p15 = pp[240];
        const float w0 = v0*p0 + v1*p4 + v2*p8  + v3*p12;
        const float w1 = v0*p1 + v1*p5 + v2*p9  + v3*p13;
        const float w2 = v0*p2 + v1*p6 + v2*p10 + v3*p14;
        const float w3 = v0*p3 + v1*p7 + v2*p11 + v3*p15;
        const float rn = 1.f / (sqrtf(w0*w0 + w1*w1 + w2*w2 + w3*w3) + 1e-30f);
        v0 = w0*rn; v1 = w1*rn; v2 = w2*rn; v3 = w3*rn;
    }
    float u0 = 1.f, u1 = 0.f, u2 = 0.f, u3 = 0.f;
    #pragma unroll 1
    for (int t = 15; t > s; --t) {
        const float* pp = &sP[t * 264 + bb];
        const float p0  = pp[0],    p1  = pp[16],   p2  = pp[32],   p3  = pp[48];
        const float p4  = pp[64],   p5  = pp[80],   p6  = pp[96],   p7  = pp[112];
        const float p8  = pp[128],  p9  = pp[144],  p10 = pp[160],  p11 = pp[176];
        const float p12 = pp[192],  p13 = pp[208],  p14 = pp[224],  p15 = pp[240];
        const float w0 = p0*u0  + p1*u1  + p2*u2  + p3*u3;
        const float w1 = p4*u0  + p5*u1  + p6*u2  + p7*u3;
        const float w2 = p8*u0  + p9*u1  + p10*u2 + p11*u3;
        const float w3 = p12*u0 + p13*u1 + p14*u2 + p15*u3;
        const float rn = 1.f / (sqrtf(w0*w0 + w1*w1 + w2*w2 + w3*w3) + 1e-30f);
        u0 = w0*rn; u1 = w1*rn; u2 = w2*rn; u3 = w3*rn;
    }

    // ---- phase 3a: forward walk, vl per site (rebuild M) -----------------
    float vlA[4], vlB[4], vlC[4], vlD[4];
    {
        float a0 = v0, a1 = v1, a2 = v2, a3 = v3;
        #pragma unroll
        for (int k = 0; k < 4; ++k) {
            vlA[k] = a0; vlB[k] = a1; vlC[k] = a2; vlD[k] = a3;
            if (k == 3) break;
            float Mm[16];
            build_M(A, n0 + k, xa[k], xc[k], Mm);
            const float t0 = a0*Mm[0] + a1*Mm[4] + a2*Mm[8]  + a3*Mm[12];
            const float t1 = a0*Mm[1] + a1*Mm[5] + a2*Mm[9]  + a3*Mm[13];
            const float t2 = a0*Mm[2] + a1*Mm[6] + a2*Mm[10] + a3*Mm[14];
            const float t3 = a0*Mm[3] + a1*Mm[7] + a2*Mm[11] + a3*Mm[15];
            a0 = t0; a1 = t1; a2 = t2; a3 = t3;
        }
    }

    // ---- phase 3b: backward walk + fused epilogue -> sXY -----------------
    const float sc = scale[0];
    #pragma unroll
    for (int kk = 3; kk >= 0; --kk) {
        const int n = n0 + kk;

        const float arn = 1.f / (sqrtf(u0*u0 + u1*u1 + u2*u2 + u3*u3) + EPS);
        float aa0 = u0*arn, aa1 = u1*arn, aa2 = u2*arn, aa3 = u3*arn;
        if (n == 63) { aa0 = 1.f; aa1 = aa2 = aa3 = 0.f; }

        const float wn = 1.f / (sqrtf(vlA[kk]*vlA[kk] + vlB[kk]*vlB[kk] +
                                      vlC[kk]*vlC[kk] + vlD[kk]*vlD[kk]) + EPS);
        float vv0 = vlA[kk]*wn, vv1 = vlB[kk]*wn, vv2 = vlC[kk]*wn, vv3 = vlD[kk]*wn;
        if (n == 0) { vv0 = 1.f; vv1 = vv2 = vv3 = 0.f; }

        const float vv[4] = {vv0, vv1, vv2, vv3};
        const float aa[4] = {aa0, aa1, aa2, aa3};
        const float4* Bq = (const float4*)Bw + (size_t)n * 16;
        float H00 = 0.f, H01 = 0.f, H10 = 0.f, H11 = 0.f;
        #pragma unroll
        for (int half = 0; half < 2; ++half) {       // 8 float4 live at a time
            float4 bq[8];
            #pragma unroll
            for (int t = 0; t < 8; ++t) bq[t] = Bq[half * 8 + t];
            #pragma unroll
            for (int i2 = 0; i2 < 2; ++i2) {
                const int i = half * 2 + i2;
                #pragma unroll
                for (int l = 0; l < 4; ++l) {
                    const float  c = vv[i] * aa[l];
                    const float4 q = bq[i2 * 4 + l];
                    H00 = fmaf(c, q.x, H00);
                    H01 = fmaf(c, q.y, H01);
                    H10 = fmaf(c, q.z, H10);
                    H11 = fmaf(c, q.w, H11);
                }
            }
        }
        const float rh = sc / (sqrtf(H00*H00 + H01*H01 + H10*H10 + H11*H11) + EPS);
        H00 *= rh; H01 *= rh; H10 *= rh; H11 *= rh;
        if (__builtin_isnan(H00)) H00 = 0.f;
        if (__builtin_isnan(H01)) H01 = 0.f;
        if (__builtin_isnan(H10)) H10 = 0.f;
        if (__builtin_isnan(H11)) H11 = 0.f;
        H00 = fmaxf(H00, 0.f); H01 = fmaxf(H01, 0.f);
        H10 = fmaxf(H10, 0.f); H11 = fmaxf(H11, 0.f);

        float2 yo;
        yo.x = fmaf(H01, xc[kk], H00 * xa[kk]);
        yo.y = fmaf(H11, xc[kk], H10 * xa[kk]);
        *(float2*)&sXY[bb * 130 + 2 * n] = yo;

        if (kk > 0) {   // u <- M[n].u  (raw suffix for site n-1)
            float Mm[16];
            build_M(A, n, xa[kk], xc[kk], Mm);
            const float t0 = Mm[0]*u0  + Mm[1]*u1  + Mm[2]*u2  + Mm[3]*u3;
            const float t1 = Mm[4]*u0  + Mm[5]*u1  + Mm[6]*u2  + Mm[7]*u3;
            const float t2 = Mm[8]*u0  + Mm[9]*u1  + Mm[10]*u2 + Mm[11]*u3;
            const float t3 = Mm[12]*u0 + Mm[13]*u1 + Mm[14]*u2 + Mm[15]*u3;
            u0 = t0; u1 = t1; u2 = t2; u3 = t3;
        }
    }
    __syncthreads();

    // ---- y out: fully coalesced float4 stores ----------------------------
    {
        float4* yg = (float4*)y + (size_t)blockIdx.x * 512;
        #pragma unroll
        for (int it = 0; it < 2; ++it) {
            const int g = it * 256 + tid;
            const int c = g >> 5, f = (g & 31) * 4;
            const float2 a = *(const float2*)&sXY[c * 130 + f];
            const float2 b = *(const float2*)&sXY[c * 130 + f + 2];
            yg[g] = make_float4(a.x, a.y, b.x, b.y);
        }
    }
}

extern "C" void kernel_launch(void* const* d_in, const int* in_sizes, int n_in,
                              void* d_out, int out_size, void* d_ws, size_t ws_size,
                              hipStream_t stream) {
    const float* x     = (const float*)d_in[0];
    const float* A     = (const float*)d_in[1];
    const float* B     = (const float*)d_in[2];
    const float* scale = (const float*)d_in[3];
    float* yp = (float*)d_out;
    const int batch  = in_sizes[0] / 128;    // 16384
    const int blocks = batch / 16;           // 1024 blocks x 256 threads
    tdvp_kernel<<<blocks, 256, 0, stream>>>(x, A, B, scale, yp);
}